// Round 7
// baseline (127.395 us; speedup 1.0000x reference)
//
#include <hip/hip_runtime.h>
#include <math.h>

static constexpr int B_  = 4;
static constexpr int TQ  = 128;
static constexpr int TK  = 512;
static constexpr int NN  = 1024;
static constexpr int QS  = 1024;
static constexpr int VS  = 1024;
static constexpr int OS  = 1024;

#define K2F    2.8853900817779268f   // 2*log2(e)
#define LOG2EF 1.4426950408889634f

typedef __attribute__((ext_vector_type(8))) short bf16x8;
typedef __attribute__((ext_vector_type(4))) float f32x4;

#define MFMA16(a,b,c) __builtin_amdgcn_mfma_f32_16x16x32_bf16((a),(b),(c),0,0,0)

// f32 -> bf16 round-to-nearest-even
__device__ __forceinline__ ushort bf16_rne(float x) {
    uint u = __float_as_uint(x);
    u += 0x7FFFu + ((u >> 16) & 1u);
    return (ushort)(u >> 16);
}
// split f32 into hi+lo bf16 (a ~= hi + lo, rel err ~2^-17)
__device__ __forceinline__ void split2(float x, ushort& h, ushort& l) {
    ushort hh = bf16_rne(x);
    float hv = __uint_as_float((uint)hh << 16);
    h = hh;
    l = bf16_rne(x - hv);
}

// ---------------------------------------------------------------------------
// [1] fused conversion: Q (512 blk), Wq (1024 blk), Wout (2048 blk) -> hi/lo
// ---------------------------------------------------------------------------
__global__ __launch_bounds__(256) void cvt_fused_kernel(
    const float* __restrict__ Q, const float* __restrict__ Wq,
    const float* __restrict__ Wo,
    ushort* __restrict__ Qh, ushort* __restrict__ Ql,
    ushort* __restrict__ Wqh, ushort* __restrict__ Wql,
    ushort* __restrict__ Woh, ushort* __restrict__ Wol)
{
    int bid = blockIdx.x;
    const float* src; ushort *h, *l; int idx;
    if (bid < 512)       { src = Q;  h = Qh;  l = Ql;  idx = bid*256 + threadIdx.x; }
    else if (bid < 1536) { src = Wq; h = Wqh; l = Wql; idx = (bid-512)*256 + threadIdx.x; }
    else                 { src = Wo; h = Woh; l = Wol; idx = (bid-1536)*256 + threadIdx.x; }
    float4 v = ((const float4*)src)[idx];
    ushort4 hh, ll;
    split2(v.x, hh.x, ll.x); split2(v.y, hh.y, ll.y);
    split2(v.z, hh.z, ll.z); split2(v.w, hh.w, ll.w);
    ((ushort4*)h)[idx] = hh;
    ((ushort4*)l)[idx] = ll;
}

// ---------------------------------------------------------------------------
// [2] V [b][k=512][v=1024] -> Vt hi/lo [b][v=1024][k=512]
// ---------------------------------------------------------------------------
__global__ __launch_bounds__(256) void cvt_transpose_v_kernel(
    const float* __restrict__ V, ushort* __restrict__ Th, ushort* __restrict__ Tl)
{
    __shared__ float tile[64][65];
    const int b = blockIdx.z, k0 = blockIdx.y * 64, v0 = blockIdx.x * 64;
    const int t = threadIdx.x;
    const float* src = V + ((size_t)b*TK + k0)*VS + v0;
    #pragma unroll
    for (int p = 0; p < 4; ++p) {
        int r = (t >> 4) + p*16, c = (t & 15) * 4;
        float4 vv = *(const float4*)(src + (size_t)r*VS + c);
        tile[r][c] = vv.x; tile[r][c+1] = vv.y; tile[r][c+2] = vv.z; tile[r][c+3] = vv.w;
    }
    __syncthreads();
    ushort* dh = Th + (size_t)b*(VS*TK) + (size_t)v0*TK + k0;
    ushort* dl = Tl + (size_t)b*(VS*TK) + (size_t)v0*TK + k0;
    #pragma unroll
    for (int p = 0; p < 4; ++p) {
        int vr = (t >> 4) + p*16, kc = (t & 15) * 4;
        ushort4 hh, ll;
        split2(tile[kc+0][vr], hh.x, ll.x);
        split2(tile[kc+1][vr], hh.y, ll.y);
        split2(tile[kc+2][vr], hh.z, ll.z);
        split2(tile[kc+3][vr], hh.w, ll.w);
        *(ushort4*)(dh + (size_t)vr*TK + kc) = hh;
        *(ushort4*)(dl + (size_t)vr*TK + kc) = ll;
    }
}

// ---------------------------------------------------------------------------
// [3/7] split-bf16 NT MFMA GEMM, M=512; 64x64 tile, 4 waves x 32x32,
// K-split via blockIdx.z (round-3 proven structure).
// ---------------------------------------------------------------------------
__global__ __launch_bounds__(256) void mfma_nt_kernel(
    const ushort* __restrict__ Ah, const ushort* __restrict__ Al,
    const ushort* __restrict__ Bh, const ushort* __restrict__ Bl,
    float* __restrict__ Cp, int lda, int ldb, int Nout, int kchunk, int bstride)
{
    __shared__ alignas(16) ushort lA[2][64][40];
    __shared__ alignas(16) ushort lB[2][64][40];
    const int t = threadIdx.x;
    const int m0 = blockIdx.y * 64, n0 = blockIdx.x * 64, kz = blockIdx.z;
    const int k0 = kz * kchunk;
    const int batch = m0 >> 7;
    const ushort* bhp = Bh + (size_t)batch * bstride;
    const ushort* blp = Bl + (size_t)batch * bstride;
    const int srow = t >> 2, skc = (t & 3) * 8;
    const int lane = t & 63, w = t >> 6;
    const int wm = (w >> 1) * 32, wn = (w & 1) * 32;
    const int fr = lane & 15, fg = (lane >> 4) * 8;

    f32x4 acc00 = {0,0,0,0}, acc01 = {0,0,0,0}, acc10 = {0,0,0,0}, acc11 = {0,0,0,0};

    for (int kb = k0; kb < k0 + kchunk; kb += 32) {
        uint4 va_h = *(const uint4*)(Ah  + (size_t)(m0+srow)*lda + kb + skc);
        uint4 va_l = *(const uint4*)(Al  + (size_t)(m0+srow)*lda + kb + skc);
        uint4 vb_h = *(const uint4*)(bhp + (size_t)(n0+srow)*ldb + kb + skc);
        uint4 vb_l = *(const uint4*)(blp + (size_t)(n0+srow)*ldb + kb + skc);
        *(uint4*)&lA[0][srow][skc] = va_h;
        *(uint4*)&lA[1][srow][skc] = va_l;
        *(uint4*)&lB[0][srow][skc] = vb_h;
        *(uint4*)&lB[1][srow][skc] = vb_l;
        __syncthreads();
        bf16x8 ah0 = *(const bf16x8*)&lA[0][wm + fr     ][fg];
        bf16x8 ah1 = *(const bf16x8*)&lA[0][wm + 16 + fr][fg];
        bf16x8 al0 = *(const bf16x8*)&lA[1][wm + fr     ][fg];
        bf16x8 al1 = *(const bf16x8*)&lA[1][wm + 16 + fr][fg];
        bf16x8 bh0 = *(const bf16x8*)&lB[0][wn + fr     ][fg];
        bf16x8 bh1 = *(const bf16x8*)&lB[0][wn + 16 + fr][fg];
        bf16x8 bl0 = *(const bf16x8*)&lB[1][wn + fr     ][fg];
        bf16x8 bl1 = *(const bf16x8*)&lB[1][wn + 16 + fr][fg];
        acc00 = MFMA16(ah0, bh0, acc00);
        acc00 = MFMA16(al0, bh0, acc00);
        acc00 = MFMA16(ah0, bl0, acc00);
        acc01 = MFMA16(ah0, bh1, acc01);
        acc01 = MFMA16(al0, bh1, acc01);
        acc01 = MFMA16(ah0, bl1, acc01);
        acc10 = MFMA16(ah1, bh0, acc10);
        acc10 = MFMA16(al1, bh0, acc10);
        acc10 = MFMA16(ah1, bl0, acc10);
        acc11 = MFMA16(ah1, bh1, acc11);
        acc11 = MFMA16(al1, bh1, acc11);
        acc11 = MFMA16(ah1, bl1, acc11);
        __syncthreads();
    }
    float* o = Cp + (size_t)kz * 512 * Nout;
    const int orow = (lane >> 4) * 4;
    #pragma unroll
    for (int r2 = 0; r2 < 4; ++r2) {
        o[(size_t)(m0+wm+orow+r2)*Nout      + n0+wn+fr]      = acc00[r2];
        o[(size_t)(m0+wm+orow+r2)*Nout      + n0+wn+16+fr]   = acc01[r2];
        o[(size_t)(m0+wm+16+orow+r2)*Nout   + n0+wn+fr]      = acc10[r2];
        o[(size_t)(m0+wm+16+orow+r2)*Nout   + n0+wn+16+fr]   = acc11[r2];
    }
}

// ---------------------------------------------------------------------------
// [9] out-GEMM MFMA: A = [Q | Cx] by kz (K=2048 split 4), B = Wout hi/lo
// ---------------------------------------------------------------------------
__global__ __launch_bounds__(256) void mfma_out_kernel(
    const ushort* __restrict__ Qh, const ushort* __restrict__ Ql,
    const ushort* __restrict__ Cxh, const ushort* __restrict__ Cxl,
    const ushort* __restrict__ Wh, const ushort* __restrict__ Wl,
    float* __restrict__ Fp)
{
    __shared__ alignas(16) ushort lA[2][64][40];
    __shared__ alignas(16) ushort lB[2][64][40];
    const int t = threadIdx.x;
    const int m0 = blockIdx.y * 64, n0 = blockIdx.x * 64, kz = blockIdx.z;
    const ushort* ah_p = (kz < 2) ? Qh : Cxh;
    const ushort* al_p = (kz < 2) ? Ql : Cxl;
    const int akoff = (kz & 1) * 512;
    const int bkoff = kz * 512;
    const int srow = t >> 2, skc = (t & 3) * 8;
    const int lane = t & 63, w = t >> 6;
    const int wm = (w >> 1) * 32, wn = (w & 1) * 32;
    const int fr = lane & 15, fg = (lane >> 4) * 8;

    f32x4 acc00 = {0,0,0,0}, acc01 = {0,0,0,0}, acc10 = {0,0,0,0}, acc11 = {0,0,0,0};

    for (int kk = 0; kk < 512; kk += 32) {
        uint4 va_h = *(const uint4*)(ah_p + (size_t)(m0+srow)*1024 + akoff + kk + skc);
        uint4 va_l = *(const uint4*)(al_p + (size_t)(m0+srow)*1024 + akoff + kk + skc);
        uint4 vb_h = *(const uint4*)(Wh   + (size_t)(n0+srow)*2048 + bkoff + kk + skc);
        uint4 vb_l = *(const uint4*)(Wl   + (size_t)(n0+srow)*2048 + bkoff + kk + skc);
        *(uint4*)&lA[0][srow][skc] = va_h;
        *(uint4*)&lA[1][srow][skc] = va_l;
        *(uint4*)&lB[0][srow][skc] = vb_h;
        *(uint4*)&lB[1][srow][skc] = vb_l;
        __syncthreads();
        bf16x8 ah0 = *(const bf16x8*)&lA[0][wm + fr     ][fg];
        bf16x8 ah1 = *(const bf16x8*)&lA[0][wm + 16 + fr][fg];
        bf16x8 al0 = *(const bf16x8*)&lA[1][wm + fr     ][fg];
        bf16x8 al1 = *(const bf16x8*)&lA[1][wm + 16 + fr][fg];
        bf16x8 bh0 = *(const bf16x8*)&lB[0][wn + fr     ][fg];
        bf16x8 bh1 = *(const bf16x8*)&lB[0][wn + 16 + fr][fg];
        bf16x8 bl0 = *(const bf16x8*)&lB[1][wn + fr     ][fg];
        bf16x8 bl1 = *(const bf16x8*)&lB[1][wn + 16 + fr][fg];
        acc00 = MFMA16(ah0, bh0, acc00);
        acc00 = MFMA16(al0, bh0, acc00);
        acc00 = MFMA16(ah0, bl0, acc00);
        acc01 = MFMA16(ah0, bh1, acc01);
        acc01 = MFMA16(al0, bh1, acc01);
        acc01 = MFMA16(ah0, bl1, acc01);
        acc10 = MFMA16(ah1, bh0, acc10);
        acc10 = MFMA16(al1, bh0, acc10);
        acc10 = MFMA16(ah1, bl0, acc10);
        acc11 = MFMA16(ah1, bh1, acc11);
        acc11 = MFMA16(al1, bh1, acc11);
        acc11 = MFMA16(ah1, bl1, acc11);
        __syncthreads();
    }
    float* o = Fp + (size_t)kz * 512 * 1024;
    const int orow = (lane >> 4) * 4;
    #pragma unroll
    for (int r2 = 0; r2 < 4; ++r2) {
        o[(size_t)(m0+wm+orow+r2)*1024    + n0+wn+fr]    = acc00[r2];
        o[(size_t)(m0+wm+orow+r2)*1024    + n0+wn+16+fr] = acc01[r2];
        o[(size_t)(m0+wm+16+orow+r2)*1024 + n0+wn+fr]    = acc10[r2];
        o[(size_t)(m0+wm+16+orow+r2)*1024 + n0+wn+16+fr] = acc11[r2];
    }
}

// ---------------------------------------------------------------------------
// [4] Ea = exp2((p0+p1+bq)*2log2e)
// ---------------------------------------------------------------------------
__global__ __launch_bounds__(256) void exp_combine_kernel(
    const float* __restrict__ Ap, const float* __restrict__ bias,
    float* __restrict__ E)
{
    int i = blockIdx.x * 256 + threadIdx.x;
    float4 p0 = ((const float4*)Ap)[i];
    float4 p1 = ((const float4*)(Ap + (size_t)B_*TQ*NN))[i];
    float4 bb = ((const float4*)bias)[i & 255];
    float4 r;
    r.x = exp2f((p0.x + p1.x + bb.x) * K2F);
    r.y = exp2f((p0.y + p1.y + bb.y) * K2F);
    r.z = exp2f((p0.z + p1.z + bb.z) * K2F);
    r.w = exp2f((p0.w + p1.w + bb.w) * K2F);
    ((float4*)E)[i] = r;
}

// ---------------------------------------------------------------------------
// [5] scores v4: LDS-broadcast operands.
// Block: 512 thr (8 waves), covers 64 k (lane=k) x 64 q (8 q/wave) x 64 n.
// Ea slice + watt staged in LDS once (1 barrier); inner reads are uniform
// ds_read_b128 broadcasts. Keys chunk in 16 named float4 VGPRs.
// Paired-rcp: w0/A + w1/B = (w0*B + w1*A) * rcp(A*B).
// ---------------------------------------------------------------------------
__global__ __launch_bounds__(512, 4) void score_lds_kernel(
    const float* __restrict__ Ea,   // [512, 1024]
    const float* __restrict__ keys, // [2048, 1024]
    const float* __restrict__ watt, // [1024]
    float* __restrict__ Sp)         // [16][512][512]
{
    __shared__ float ea_lds[64][64];
    __shared__ float w_lds[64];
    const int tid  = threadIdx.x;
    const int lane = tid & 63;
    const int wid  = tid >> 6;          // 0..7
    const int kt = blockIdx.x;          // 0..7
    const int b  = blockIdx.y;          // 0..3
    const int z  = blockIdx.z;          // 0..31
    const int nh = z & 15, qh = z >> 4;
    const int nbeg = nh * 64;
    const int q0base = b*TQ + qh*64;
    const int krow = b*TK + kt*64 + lane;

    // stage Ea[q0base..+64][nbeg..+64] (16 KB) + watt[nbeg..+64] into LDS
    {
        int r = tid >> 3, c = (tid & 7) * 8;
        const float* src = Ea + (size_t)(q0base + r)*NN + nbeg + c;
        *(float4*)&ea_lds[r][c]     = *(const float4*)(src);
        *(float4*)&ea_lds[r][c + 4] = *(const float4*)(src + 4);
        if (tid < 64) w_lds[tid] = watt[nbeg + tid];
    }
    // per-lane keys chunk -> exp2 -> 16 named float4 (registers)
    const float* kp = keys + (size_t)krow*NN + nbeg;
    float4 ek[16];
    #pragma unroll
    for (int g = 0; g < 16; ++g) {
        float4 kv = *(const float4*)(kp + g*4);
        ek[g].x = exp2f(kv.x * K2F);
        ek[g].y = exp2f(kv.y * K2F);
        ek[g].z = exp2f(kv.z * K2F);
        ek[g].w = exp2f(kv.w * K2F);
    }
    __syncthreads();

    const float4* wv = (const float4*)w_lds;
    float* op = Sp + ((size_t)nh*512 + q0base + wid*8)*TK + kt*64 + lane;
    for (int qi = 0; qi < 8; ++qi) {
        const float4* ev = (const float4*)&ea_lds[wid*8 + qi][0];
        float s0 = 0.f, s1 = 0.f;
        #pragma unroll
        for (int g = 0; g < 16; ++g) {
            float4 ea4 = ev[g];
            float4 w4  = wv[g];
            float A  = fmaf(ea4.x, ek[g].x, 1.0f);
            float Bv = fmaf(ea4.y, ek[g].y, 1.0f);
            float C  = fmaf(ea4.z, ek[g].z, 1.0f);
            float D  = fmaf(ea4.w, ek[g].w, 1.0f);
            float num0 = fmaf(w4.x, Bv, w4.y * A);
            float num1 = fmaf(w4.z, D,  w4.w * C);
            s0 = fmaf(num0, __builtin_amdgcn_rcpf(A * Bv), s0);
            s1 = fmaf(num1, __builtin_amdgcn_rcpf(C * D),  s1);
        }
        *op = s0 + s1;
        op += TK;
    }
}

// ---------------------------------------------------------------------------
// [6] softmax over k of (-2 * sum_{h<16} Sp[h]); writes P f32 + Ph/Pl
// ---------------------------------------------------------------------------
__global__ __launch_bounds__(256) void softmax_kernel(
    const float* __restrict__ Sp, float* __restrict__ P,
    ushort* __restrict__ Ph, ushort* __restrict__ Pl)
{
    const int lane = threadIdx.x & 63;
    const int wid  = threadIdx.x >> 6;
    const int row  = blockIdx.x * 4 + wid;
    const size_t S = (size_t)512*512;
    float v[8];
    float m = -3.4e38f;
    #pragma unroll
    for (int j = 0; j < 8; ++j) {
        int k = lane + j*64;
        float s = 0.f;
        #pragma unroll
        for (int h = 0; h < 16; ++h)
            s += Sp[h*S + (size_t)row*TK + k];
        v[j] = -2.0f * s;
        m = fmaxf(m, v[j]);
    }
    #pragma unroll
    for (int off = 32; off; off >>= 1) m = fmaxf(m, __shfl_xor(m, off, 64));
    float sum = 0.f;
    #pragma unroll
    for (int j = 0; j < 8; ++j) { v[j] = exp2f((v[j] - m) * LOG2EF); sum += v[j]; }
    #pragma unroll
    for (int off = 32; off; off >>= 1) sum += __shfl_xor(sum, off, 64);
    float inv = 1.0f / sum;
    #pragma unroll
    for (int j = 0; j < 8; ++j) {
        int k = lane + j*64;
        float pv = v[j] * inv;
        P[(size_t)row * TK + k] = pv;
        ushort h, l; split2(pv, h, l);
        Ph[(size_t)row * TK + k] = h;
        Pl[(size_t)row * TK + k] = l;
    }
}

// ---------------------------------------------------------------------------
// [8] Cx = Ep0+Ep1 -> hi/lo bf16
// ---------------------------------------------------------------------------
__global__ __launch_bounds__(256) void combine_cvt_kernel(
    const float* __restrict__ Ep, ushort* __restrict__ Ch, ushort* __restrict__ Cl)
{
    int i = blockIdx.x * 256 + threadIdx.x;
    float4 p0 = ((const float4*)Ep)[i];
    float4 p1 = ((const float4*)(Ep + (size_t)B_*TQ*VS))[i];
    float4 s = {p0.x+p1.x, p0.y+p1.y, p0.z+p1.z, p0.w+p1.w};
    ushort4 hh, ll;
    split2(s.x, hh.x, ll.x); split2(s.y, hh.y, ll.y);
    split2(s.z, hh.z, ll.z); split2(s.w, hh.w, ll.w);
    ((ushort4*)Ch)[i] = hh;
    ((ushort4*)Cl)[i] = ll;
}

// ---------------------------------------------------------------------------
// [10] out = tanh(sum Fp + bias)
// ---------------------------------------------------------------------------
__global__ __launch_bounds__(256) void tanh_combine_kernel(
    const float* __restrict__ Fp, const float* __restrict__ bias,
    float* __restrict__ out)
{
    int i = blockIdx.x * 256 + threadIdx.x;
    const size_t S = (size_t)B_*TQ*OS;
    float4 p0 = ((const float4*)Fp)[i];
    float4 p1 = ((const float4*)(Fp + S))[i];
    float4 p2 = ((const float4*)(Fp + 2*S))[i];
    float4 p3 = ((const float4*)(Fp + 3*S))[i];
    float4 bb = ((const float4*)bias)[i & 255];
    float4 r;
    r.x = tanhf(p0.x + p1.x + p2.x + p3.x + bb.x);
    r.y = tanhf(p0.y + p1.y + p2.y + p3.y + bb.y);
    r.z = tanhf(p0.z + p1.z + p2.z + p3.z + bb.z);
    r.w = tanhf(p0.w + p1.w + p2.w + p3.w + bb.w);
    ((float4*)out)[i] = r;
}

// ---------------------------------------------------------------------------
extern "C" void kernel_launch(void* const* d_in, const int* in_sizes, int n_in,
                              void* d_out, int out_size, void* d_ws, size_t ws_size,
                              hipStream_t stream)
{
    const float* query  = (const float*)d_in[0];
    const float* keys   = (const float*)d_in[1];
    const float* values = (const float*)d_in[2];
    const float* Wq     = (const float*)d_in[3];
    const float* bq     = (const float*)d_in[4];
    const float* watt   = (const float*)d_in[5];
    // d_in[6] = b_att: dropped (softmax shift-invariance)
    const float* Wout   = (const float*)d_in[7];
    const float* bout   = (const float*)d_in[8];

    float* out = (float*)d_out;                    // output 0 (524288 f32)
    float* P   = out + (size_t)B_*TQ*OS;           // output 1 (262144 f32)

    // ws: fully disjoint layout, 59 MB used (256 MiB available).
    char* base = (char*)d_ws;
    const size_t MB = 1u << 20;
    ushort* Qh  = (ushort*)(base +  0*MB);
    ushort* Ql  = (ushort*)(base +  1*MB);
    ushort* Wqh = (ushort*)(base +  2*MB);
    ushort* Wql = (ushort*)(base +  4*MB);
    ushort* Woh = (ushort*)(base +  6*MB);
    ushort* Wol = (ushort*)(base + 10*MB);
    ushort* Vth = (ushort*)(base + 14*MB);
    ushort* Vtl = (ushort*)(base + 18*MB);
    float*  Ap  = (float*) (base + 22*MB);   // [2][512][1024]
    float*  Ea  = (float*) (base + 26*MB);   // [512][1024]
    float*  Sp  = (float*) (base + 28*MB);   // [16][512][512] = 16 MB
    ushort* Ph  = (ushort*)(base + 44*MB);
    ushort* Pl  = (ushort*)(base + 44*MB + 512*1024);
    float*  Ep  = (float*) (base + 45*MB);   // [2][512][1024]
    ushort* Cxh = (ushort*)(base + 49*MB);
    ushort* Cxl = (ushort*)(base + 50*MB);
    float*  Fp  = (float*) (base + 51*MB);   // [4][512][1024]

    // [1] convert Q, Wq, Wout to hi/lo bf16
    cvt_fused_kernel<<<dim3(3584), dim3(256), 0, stream>>>(
        query, Wq, Wout, Qh, Ql, Wqh, Wql, Woh, Wol);
    // [2] V transpose + convert
    cvt_transpose_v_kernel<<<dim3(16, 8, 4), dim3(256), 0, stream>>>(values, Vth, Vtl);
    // [3] A-GEMM partials: Q @ Wq^T  (K=1024 split 2)
    mfma_nt_kernel<<<dim3(16, 8, 2), dim3(256), 0, stream>>>(
        Qh, Ql, Wqh, Wql, Ap, 1024, 1024, 1024, 512, 0);
    // [4] Ea = e^{2*(Aq+bq)}
    exp_combine_kernel<<<dim3(512), dim3(256), 0, stream>>>(Ap, bq, Ea);
    // [5] scores (LDS-broadcast operands, paired-rcp)
    score_lds_kernel<<<dim3(8, 4, 32), dim3(512), 0, stream>>>(Ea, keys, watt, Sp);
    // [6] softmax -> P (output 1) + Ph/Pl
    softmax_kernel<<<dim3(128), dim3(256), 0, stream>>>(Sp, P, Ph, Pl);
    // [7] PV partials: P @ V (per-batch, K=512 split 2)
    mfma_nt_kernel<<<dim3(16, 8, 2), dim3(256), 0, stream>>>(
        Ph, Pl, Vth, Vtl, Ep, 512, 512, 1024, 256, VS*TK);
    // [8] Cx hi/lo
    combine_cvt_kernel<<<dim3(512), dim3(256), 0, stream>>>(Ep, Cxh, Cxl);
    // [9] out-GEMM partials (K=2048 split 4)
    mfma_out_kernel<<<dim3(16, 8, 4), dim3(256), 0, stream>>>(
        Qh, Ql, Cxh, Cxl, Woh, Wol, Fp);
    // [10] out = tanh(sum + bout)
    tanh_combine_kernel<<<dim3(512), dim3(256), 0, stream>>>(Fp, bout, out);
}

// Round 8
// 89.333 us; speedup vs baseline: 1.4261x; 1.4261x over previous
//
#include <hip/hip_runtime.h>
#include <math.h>

static constexpr int B_  = 4;
static constexpr int TQ  = 128;
static constexpr int TK  = 512;
static constexpr int NN  = 1024;
static constexpr int QS  = 1024;
static constexpr int VS  = 1024;
static constexpr int OS  = 1024;

#define K2F    2.8853900817779268f   // 2*log2(e)
#define LOG2EF 1.4426950408889634f

typedef __attribute__((ext_vector_type(8))) short bf16x8;
typedef __attribute__((ext_vector_type(4))) float f32x4;

#define MFMA16(a,b,c) __builtin_amdgcn_mfma_f32_16x16x32_bf16((a),(b),(c),0,0,0)

// f32 -> bf16 round-to-nearest-even
__device__ __forceinline__ ushort bf16_rne(float x) {
    uint u = __float_as_uint(x);
    u += 0x7FFFu + ((u >> 16) & 1u);
    return (ushort)(u >> 16);
}
// split f32 into hi+lo bf16 (a ~= hi + lo, rel err ~2^-17)
__device__ __forceinline__ void split2(float x, ushort& h, ushort& l) {
    ushort hh = bf16_rne(x);
    float hv = __uint_as_float((uint)hh << 16);
    h = hh;
    l = bf16_rne(x - hv);
}

// ---------------------------------------------------------------------------
// [1] unified conversion: Q / Wq / Wout -> hi/lo  +  V transpose -> hi/lo
// blocks: [0,512) Q, [512,1536) Wq, [1536,3584) Wout, [3584,4096) V-transpose
// ---------------------------------------------------------------------------
__global__ __launch_bounds__(256) void cvt_all_kernel(
    const float* __restrict__ Q, const float* __restrict__ Wq,
    const float* __restrict__ Wo, const float* __restrict__ V,
    ushort* __restrict__ Qh, ushort* __restrict__ Ql,
    ushort* __restrict__ Wqh, ushort* __restrict__ Wql,
    ushort* __restrict__ Woh, ushort* __restrict__ Wol,
    ushort* __restrict__ Vth, ushort* __restrict__ Vtl)
{
    __shared__ float tile[64][65];
    const int bid = blockIdx.x;
    const int t = threadIdx.x;
    if (bid < 3584) {
        const float* src; ushort *h, *l; int idx;
        if (bid < 512)       { src = Q;  h = Qh;  l = Ql;  idx = bid*256 + t; }
        else if (bid < 1536) { src = Wq; h = Wqh; l = Wql; idx = (bid-512)*256 + t; }
        else                 { src = Wo; h = Woh; l = Wol; idx = (bid-1536)*256 + t; }
        float4 v = ((const float4*)src)[idx];
        ushort4 hh, ll;
        split2(v.x, hh.x, ll.x); split2(v.y, hh.y, ll.y);
        split2(v.z, hh.z, ll.z); split2(v.w, hh.w, ll.w);
        ((ushort4*)h)[idx] = hh;
        ((ushort4*)l)[idx] = ll;
        return;
    }
    // V transpose: vid -> (v-tile 16, k-tile 8, batch 4)
    const int vid = bid - 3584;
    const int v0 = (vid & 15) * 64;
    const int k0 = ((vid >> 4) & 7) * 64;
    const int b  = vid >> 7;
    const float* src = V + ((size_t)b*TK + k0)*VS + v0;
    #pragma unroll
    for (int p = 0; p < 4; ++p) {
        int r = (t >> 4) + p*16, c = (t & 15) * 4;
        float4 vv = *(const float4*)(src + (size_t)r*VS + c);
        tile[r][c] = vv.x; tile[r][c+1] = vv.y; tile[r][c+2] = vv.z; tile[r][c+3] = vv.w;
    }
    __syncthreads();
    ushort* dh = Vth + (size_t)b*(VS*TK) + (size_t)v0*TK + k0;
    ushort* dl = Vtl + (size_t)b*(VS*TK) + (size_t)v0*TK + k0;
    #pragma unroll
    for (int p = 0; p < 4; ++p) {
        int vr = (t >> 4) + p*16, kc = (t & 15) * 4;
        ushort4 hh, ll;
        split2(tile[kc+0][vr], hh.x, ll.x);
        split2(tile[kc+1][vr], hh.y, ll.y);
        split2(tile[kc+2][vr], hh.z, ll.z);
        split2(tile[kc+3][vr], hh.w, ll.w);
        *(ushort4*)(dh + (size_t)vr*TK + kc) = hh;
        *(ushort4*)(dl + (size_t)vr*TK + kc) = ll;
    }
}

// ---------------------------------------------------------------------------
// [2/5] split-bf16 NT MFMA GEMM, M=512; 64x64 tile, 4 waves x 32x32,
// K-split via blockIdx.z (round-3 proven structure).
// ---------------------------------------------------------------------------
__global__ __launch_bounds__(256) void mfma_nt_kernel(
    const ushort* __restrict__ Ah, const ushort* __restrict__ Al,
    const ushort* __restrict__ Bh, const ushort* __restrict__ Bl,
    float* __restrict__ Cp, int lda, int ldb, int Nout, int kchunk, int bstride)
{
    __shared__ alignas(16) ushort lA[2][64][40];
    __shared__ alignas(16) ushort lB[2][64][40];
    const int t = threadIdx.x;
    const int m0 = blockIdx.y * 64, n0 = blockIdx.x * 64, kz = blockIdx.z;
    const int k0 = kz * kchunk;
    const int batch = m0 >> 7;
    const ushort* bhp = Bh + (size_t)batch * bstride;
    const ushort* blp = Bl + (size_t)batch * bstride;
    const int srow = t >> 2, skc = (t & 3) * 8;
    const int lane = t & 63, w = t >> 6;
    const int wm = (w >> 1) * 32, wn = (w & 1) * 32;
    const int fr = lane & 15, fg = (lane >> 4) * 8;

    f32x4 acc00 = {0,0,0,0}, acc01 = {0,0,0,0}, acc10 = {0,0,0,0}, acc11 = {0,0,0,0};

    for (int kb = k0; kb < k0 + kchunk; kb += 32) {
        uint4 va_h = *(const uint4*)(Ah  + (size_t)(m0+srow)*lda + kb + skc);
        uint4 va_l = *(const uint4*)(Al  + (size_t)(m0+srow)*lda + kb + skc);
        uint4 vb_h = *(const uint4*)(bhp + (size_t)(n0+srow)*ldb + kb + skc);
        uint4 vb_l = *(const uint4*)(blp + (size_t)(n0+srow)*ldb + kb + skc);
        *(uint4*)&lA[0][srow][skc] = va_h;
        *(uint4*)&lA[1][srow][skc] = va_l;
        *(uint4*)&lB[0][srow][skc] = vb_h;
        *(uint4*)&lB[1][srow][skc] = vb_l;
        __syncthreads();
        bf16x8 ah0 = *(const bf16x8*)&lA[0][wm + fr     ][fg];
        bf16x8 ah1 = *(const bf16x8*)&lA[0][wm + 16 + fr][fg];
        bf16x8 al0 = *(const bf16x8*)&lA[1][wm + fr     ][fg];
        bf16x8 al1 = *(const bf16x8*)&lA[1][wm + 16 + fr][fg];
        bf16x8 bh0 = *(const bf16x8*)&lB[0][wn + fr     ][fg];
        bf16x8 bh1 = *(const bf16x8*)&lB[0][wn + 16 + fr][fg];
        bf16x8 bl0 = *(const bf16x8*)&lB[1][wn + fr     ][fg];
        bf16x8 bl1 = *(const bf16x8*)&lB[1][wn + 16 + fr][fg];
        acc00 = MFMA16(ah0, bh0, acc00);
        acc00 = MFMA16(al0, bh0, acc00);
        acc00 = MFMA16(ah0, bl0, acc00);
        acc01 = MFMA16(ah0, bh1, acc01);
        acc01 = MFMA16(al0, bh1, acc01);
        acc01 = MFMA16(ah0, bl1, acc01);
        acc10 = MFMA16(ah1, bh0, acc10);
        acc10 = MFMA16(al1, bh0, acc10);
        acc10 = MFMA16(ah1, bl0, acc10);
        acc11 = MFMA16(ah1, bh1, acc11);
        acc11 = MFMA16(al1, bh1, acc11);
        acc11 = MFMA16(ah1, bl1, acc11);
        __syncthreads();
    }
    float* o = Cp + (size_t)kz * 512 * Nout;
    const int orow = (lane >> 4) * 4;
    #pragma unroll
    for (int r2 = 0; r2 < 4; ++r2) {
        o[(size_t)(m0+wm+orow+r2)*Nout      + n0+wn+fr]      = acc00[r2];
        o[(size_t)(m0+wm+orow+r2)*Nout      + n0+wn+16+fr]   = acc01[r2];
        o[(size_t)(m0+wm+16+orow+r2)*Nout   + n0+wn+fr]      = acc10[r2];
        o[(size_t)(m0+wm+16+orow+r2)*Nout   + n0+wn+16+fr]   = acc11[r2];
    }
}

// ---------------------------------------------------------------------------
// [7] out-GEMM MFMA: A = [Q | Cx] by kz (K=2048 split 4), B = Wout hi/lo
// ---------------------------------------------------------------------------
__global__ __launch_bounds__(256) void mfma_out_kernel(
    const ushort* __restrict__ Qh, const ushort* __restrict__ Ql,
    const ushort* __restrict__ Cxh, const ushort* __restrict__ Cxl,
    const ushort* __restrict__ Wh, const ushort* __restrict__ Wl,
    float* __restrict__ Fp)
{
    __shared__ alignas(16) ushort lA[2][64][40];
    __shared__ alignas(16) ushort lB[2][64][40];
    const int t = threadIdx.x;
    const int m0 = blockIdx.y * 64, n0 = blockIdx.x * 64, kz = blockIdx.z;
    const ushort* ah_p = (kz < 2) ? Qh : Cxh;
    const ushort* al_p = (kz < 2) ? Ql : Cxl;
    const int akoff = (kz & 1) * 512;
    const int bkoff = kz * 512;
    const int srow = t >> 2, skc = (t & 3) * 8;
    const int lane = t & 63, w = t >> 6;
    const int wm = (w >> 1) * 32, wn = (w & 1) * 32;
    const int fr = lane & 15, fg = (lane >> 4) * 8;

    f32x4 acc00 = {0,0,0,0}, acc01 = {0,0,0,0}, acc10 = {0,0,0,0}, acc11 = {0,0,0,0};

    for (int kk = 0; kk < 512; kk += 32) {
        uint4 va_h = *(const uint4*)(ah_p + (size_t)(m0+srow)*1024 + akoff + kk + skc);
        uint4 va_l = *(const uint4*)(al_p + (size_t)(m0+srow)*1024 + akoff + kk + skc);
        uint4 vb_h = *(const uint4*)(Wh   + (size_t)(n0+srow)*2048 + bkoff + kk + skc);
        uint4 vb_l = *(const uint4*)(Wl   + (size_t)(n0+srow)*2048 + bkoff + kk + skc);
        *(uint4*)&lA[0][srow][skc] = va_h;
        *(uint4*)&lA[1][srow][skc] = va_l;
        *(uint4*)&lB[0][srow][skc] = vb_h;
        *(uint4*)&lB[1][srow][skc] = vb_l;
        __syncthreads();
        bf16x8 ah0 = *(const bf16x8*)&lA[0][wm + fr     ][fg];
        bf16x8 ah1 = *(const bf16x8*)&lA[0][wm + 16 + fr][fg];
        bf16x8 al0 = *(const bf16x8*)&lA[1][wm + fr     ][fg];
        bf16x8 al1 = *(const bf16x8*)&lA[1][wm + 16 + fr][fg];
        bf16x8 bh0 = *(const bf16x8*)&lB[0][wn + fr     ][fg];
        bf16x8 bh1 = *(const bf16x8*)&lB[0][wn + 16 + fr][fg];
        bf16x8 bl0 = *(const bf16x8*)&lB[1][wn + fr     ][fg];
        bf16x8 bl1 = *(const bf16x8*)&lB[1][wn + 16 + fr][fg];
        acc00 = MFMA16(ah0, bh0, acc00);
        acc00 = MFMA16(al0, bh0, acc00);
        acc00 = MFMA16(ah0, bl0, acc00);
        acc01 = MFMA16(ah0, bh1, acc01);
        acc01 = MFMA16(al0, bh1, acc01);
        acc01 = MFMA16(ah0, bl1, acc01);
        acc10 = MFMA16(ah1, bh0, acc10);
        acc10 = MFMA16(al1, bh0, acc10);
        acc10 = MFMA16(ah1, bl0, acc10);
        acc11 = MFMA16(ah1, bh1, acc11);
        acc11 = MFMA16(al1, bh1, acc11);
        acc11 = MFMA16(ah1, bl1, acc11);
        __syncthreads();
    }
    float* o = Fp + (size_t)kz * 512 * 1024;
    const int orow = (lane >> 4) * 4;
    #pragma unroll
    for (int r2 = 0; r2 < 4; ++r2) {
        o[(size_t)(m0+wm+orow+r2)*1024    + n0+wn+fr]    = acc00[r2];
        o[(size_t)(m0+wm+orow+r2)*1024    + n0+wn+16+fr] = acc01[r2];
        o[(size_t)(m0+wm+16+orow+r2)*1024 + n0+wn+fr]    = acc10[r2];
        o[(size_t)(m0+wm+16+orow+r2)*1024 + n0+wn+16+fr] = acc11[r2];
    }
}

// ---------------------------------------------------------------------------
// [3] scores v5: 64q x 64k x 64n per block, 4x4/thread, paired-rcp.
// Full-chunk staging (exp2 of Ap-sum and keys during staging), 2 barriers.
// Grid 8x8x16 = 1024 blocks = 4096 waves.
// Sp[nh][q][k] = sum_{n-pairs} (w0*B + w1*A) * rcp(A*B)
// ---------------------------------------------------------------------------
__global__ __launch_bounds__(256) void score_v5_kernel(
    const float* __restrict__ Ap,   // [2][512][1024] A-GEMM partials
    const float* __restrict__ bq,   // [1024]
    const float* __restrict__ keys, // [2048, 1024]
    const float* __restrict__ watt, // [1024]
    float* __restrict__ Sp)         // [16][512][512]
{
    __shared__ float ea[64][68];
    __shared__ float ek[64][68];
    __shared__ float wl[64];
    const int tid = threadIdx.x;
    const int kt = blockIdx.x;      // 0..7
    const int qt = blockIdx.y;      // 0..7
    const int nh = blockIdx.z;      // 0..15
    const int nbeg = nh * 64;
    const int q0 = qt * 64;
    const int b  = qt >> 1;
    const int k0 = b*TK + kt*64;

    // stage: ea[n][q] = exp2((Ap0+Ap1+bq)*K2F), ek[n][k] = exp2(keys*K2F)
    {
        const int r = tid >> 2;          // 0..63
        const int c = (tid & 3) * 16;    // 0,16,32,48
        const float* a0 = Ap + (size_t)(q0 + r)*NN + nbeg + c;
        const float* a1 = a0 + 524288;
        const float* bb = bq + nbeg + c;
        const float* kp = keys + (size_t)(k0 + r)*NN + nbeg + c;
        #pragma unroll
        for (int j4 = 0; j4 < 4; ++j4) {
            float4 p0 = *(const float4*)(a0 + j4*4);
            float4 p1 = *(const float4*)(a1 + j4*4);
            float4 bv = *(const float4*)(bb + j4*4);
            ea[c+j4*4+0][r] = exp2f((p0.x + p1.x + bv.x) * K2F);
            ea[c+j4*4+1][r] = exp2f((p0.y + p1.y + bv.y) * K2F);
            ea[c+j4*4+2][r] = exp2f((p0.z + p1.z + bv.z) * K2F);
            ea[c+j4*4+3][r] = exp2f((p0.w + p1.w + bv.w) * K2F);
            float4 kv = *(const float4*)(kp + j4*4);
            ek[c+j4*4+0][r] = exp2f(kv.x * K2F);
            ek[c+j4*4+1][r] = exp2f(kv.y * K2F);
            ek[c+j4*4+2][r] = exp2f(kv.z * K2F);
            ek[c+j4*4+3][r] = exp2f(kv.w * K2F);
        }
        if (tid < 64) wl[tid] = watt[nbeg + tid];
    }
    __syncthreads();

    const int tx = tid & 15;        // k sub-tile
    const int ty = tid >> 4;        // q sub-tile (0..15)
    float acc[4][4] = {};
    #pragma unroll 2
    for (int g = 0; g < 16; ++g) {
        float4 e0 = *(const float4*)&ea[4*g+0][ty*4];
        float4 e1 = *(const float4*)&ea[4*g+1][ty*4];
        float4 e2 = *(const float4*)&ea[4*g+2][ty*4];
        float4 e3 = *(const float4*)&ea[4*g+3][ty*4];
        float4 f0 = *(const float4*)&ek[4*g+0][tx*4];
        float4 f1 = *(const float4*)&ek[4*g+1][tx*4];
        float4 f2 = *(const float4*)&ek[4*g+2][tx*4];
        float4 f3 = *(const float4*)&ek[4*g+3][tx*4];
        float4 w4 = *(const float4*)&wl[4*g];
        float E0[4] = {e0.x,e0.y,e0.z,e0.w};
        float E1[4] = {e1.x,e1.y,e1.z,e1.w};
        float E2[4] = {e2.x,e2.y,e2.z,e2.w};
        float E3[4] = {e3.x,e3.y,e3.z,e3.w};
        float F0[4] = {f0.x,f0.y,f0.z,f0.w};
        float F1[4] = {f1.x,f1.y,f1.z,f1.w};
        float F2[4] = {f2.x,f2.y,f2.z,f2.w};
        float F3[4] = {f3.x,f3.y,f3.z,f3.w};
        #pragma unroll
        for (int i = 0; i < 4; ++i) {
            #pragma unroll
            for (int j = 0; j < 4; ++j) {
                float A  = fmaf(E0[i], F0[j], 1.0f);
                float Bv = fmaf(E1[i], F1[j], 1.0f);
                float C  = fmaf(E2[i], F2[j], 1.0f);
                float D  = fmaf(E3[i], F3[j], 1.0f);
                float n0 = fmaf(w4.x, Bv, w4.y * A);
                float n1 = fmaf(w4.z, D,  w4.w * C);
                acc[i][j] = fmaf(n0, __builtin_amdgcn_rcpf(A * Bv), acc[i][j]);
                acc[i][j] = fmaf(n1, __builtin_amdgcn_rcpf(C * D),  acc[i][j]);
            }
        }
    }
    float* o = Sp + ((size_t)nh*512 + q0 + ty*4)*TK + kt*64 + tx*4;
    #pragma unroll
    for (int i = 0; i < 4; ++i) {
        #pragma unroll
        for (int j = 0; j < 4; ++j)
            o[(size_t)i*TK + j] = acc[i][j];
    }
}

// ---------------------------------------------------------------------------
// [4] softmax over k of (-2 * sum_{h<16} Sp[h]); writes P f32 + Ph/Pl
// ---------------------------------------------------------------------------
__global__ __launch_bounds__(256) void softmax_kernel(
    const float* __restrict__ Sp, float* __restrict__ P,
    ushort* __restrict__ Ph, ushort* __restrict__ Pl)
{
    const int lane = threadIdx.x & 63;
    const int wid  = threadIdx.x >> 6;
    const int row  = blockIdx.x * 4 + wid;
    const size_t S = (size_t)512*512;
    float v[8];
    float m = -3.4e38f;
    #pragma unroll
    for (int j = 0; j < 8; ++j) {
        int k = lane + j*64;
        float s = 0.f;
        #pragma unroll
        for (int h = 0; h < 16; ++h)
            s += Sp[h*S + (size_t)row*TK + k];
        v[j] = -2.0f * s;
        m = fmaxf(m, v[j]);
    }
    #pragma unroll
    for (int off = 32; off; off >>= 1) m = fmaxf(m, __shfl_xor(m, off, 64));
    float sum = 0.f;
    #pragma unroll
    for (int j = 0; j < 8; ++j) { v[j] = exp2f((v[j] - m) * LOG2EF); sum += v[j]; }
    #pragma unroll
    for (int off = 32; off; off >>= 1) sum += __shfl_xor(sum, off, 64);
    float inv = 1.0f / sum;
    #pragma unroll
    for (int j = 0; j < 8; ++j) {
        int k = lane + j*64;
        float pv = v[j] * inv;
        P[(size_t)row * TK + k] = pv;
        ushort h, l; split2(pv, h, l);
        Ph[(size_t)row * TK + k] = h;
        Pl[(size_t)row * TK + k] = l;
    }
}

// ---------------------------------------------------------------------------
// [6] Cx = Ep0+Ep1 -> hi/lo bf16
// ---------------------------------------------------------------------------
__global__ __launch_bounds__(256) void combine_cvt_kernel(
    const float* __restrict__ Ep, ushort* __restrict__ Ch, ushort* __restrict__ Cl)
{
    int i = blockIdx.x * 256 + threadIdx.x;
    float4 p0 = ((const float4*)Ep)[i];
    float4 p1 = ((const float4*)(Ep + (size_t)B_*TQ*VS))[i];
    float4 s = {p0.x+p1.x, p0.y+p1.y, p0.z+p1.z, p0.w+p1.w};
    ushort4 hh, ll;
    split2(s.x, hh.x, ll.x); split2(s.y, hh.y, ll.y);
    split2(s.z, hh.z, ll.z); split2(s.w, hh.w, ll.w);
    ((ushort4*)Ch)[i] = hh;
    ((ushort4*)Cl)[i] = ll;
}

// ---------------------------------------------------------------------------
// [8] out = tanh(sum Fp + bias)
// ---------------------------------------------------------------------------
__global__ __launch_bounds__(256) void tanh_combine_kernel(
    const float* __restrict__ Fp, const float* __restrict__ bias,
    float* __restrict__ out)
{
    int i = blockIdx.x * 256 + threadIdx.x;
    const size_t S = (size_t)B_*TQ*OS;
    float4 p0 = ((const float4*)Fp)[i];
    float4 p1 = ((const float4*)(Fp + S))[i];
    float4 p2 = ((const float4*)(Fp + 2*S))[i];
    float4 p3 = ((const float4*)(Fp + 3*S))[i];
    float4 bb = ((const float4*)bias)[i & 255];
    float4 r;
    r.x = tanhf(p0.x + p1.x + p2.x + p3.x + bb.x);
    r.y = tanhf(p0.y + p1.y + p2.y + p3.y + bb.y);
    r.z = tanhf(p0.z + p1.z + p2.z + p3.z + bb.z);
    r.w = tanhf(p0.w + p1.w + p2.w + p3.w + bb.w);
    ((float4*)out)[i] = r;
}

// ---------------------------------------------------------------------------
extern "C" void kernel_launch(void* const* d_in, const int* in_sizes, int n_in,
                              void* d_out, int out_size, void* d_ws, size_t ws_size,
                              hipStream_t stream)
{
    const float* query  = (const float*)d_in[0];
    const float* keys   = (const float*)d_in[1];
    const float* values = (const float*)d_in[2];
    const float* Wq     = (const float*)d_in[3];
    const float* bq     = (const float*)d_in[4];
    const float* watt   = (const float*)d_in[5];
    // d_in[6] = b_att: dropped (softmax shift-invariance)
    const float* Wout   = (const float*)d_in[7];
    const float* bout   = (const float*)d_in[8];

    float* out = (float*)d_out;                    // output 0 (524288 f32)
    float* P   = out + (size_t)B_*TQ*OS;           // output 1 (262144 f32)

    // ws: fully disjoint layout (256 MiB available).
    char* base = (char*)d_ws;
    const size_t MB = 1u << 20;
    ushort* Qh  = (ushort*)(base +  0*MB);
    ushort* Ql  = (ushort*)(base +  1*MB);
    ushort* Wqh = (ushort*)(base +  2*MB);
    ushort* Wql = (ushort*)(base +  4*MB);
    ushort* Woh = (ushort*)(base +  6*MB);
    ushort* Wol = (ushort*)(base + 10*MB);
    ushort* Vth = (ushort*)(base + 14*MB);
    ushort* Vtl = (ushort*)(base + 18*MB);
    float*  Ap  = (float*) (base + 22*MB);   // [2][512][1024]
    float*  Sp  = (float*) (base + 28*MB);   // [16][512][512] = 16 MB
    ushort* Ph  = (ushort*)(base + 44*MB);
    ushort* Pl  = (ushort*)(base + 44*MB + 512*1024);
    float*  Ep  = (float*) (base + 45*MB);   // [2][512][1024]
    ushort* Cxh = (ushort*)(base + 49*MB);
    ushort* Cxl = (ushort*)(base + 50*MB);
    float*  Fp  = (float*) (base + 51*MB);   // [4][512][1024]

    // [1] all conversions + V transpose
    cvt_all_kernel<<<dim3(4096), dim3(256), 0, stream>>>(
        query, Wq, Wout, values, Qh, Ql, Wqh, Wql, Woh, Wol, Vth, Vtl);
    // [2] A-GEMM partials: Q @ Wq^T (K=1024 split 2)
    mfma_nt_kernel<<<dim3(16, 8, 2), dim3(256), 0, stream>>>(
        Qh, Ql, Wqh, Wql, Ap, 1024, 1024, 1024, 512, 0);
    // [3] scores (fused exp of Ap-sum; full-chunk staging; paired-rcp)
    score_v5_kernel<<<dim3(8, 8, 16), dim3(256), 0, stream>>>(
        Ap, bq, keys, watt, Sp);
    // [4] softmax -> P (output 1) + Ph/Pl
    softmax_kernel<<<dim3(128), dim3(256), 0, stream>>>(Sp, P, Ph, Pl);
    // [5] PV partials: P @ V (per-batch, K=512 split 2)
    mfma_nt_kernel<<<dim3(16, 8, 2), dim3(256), 0, stream>>>(
        Ph, Pl, Vth, Vtl, Ep, 512, 512, 1024, 256, VS*TK);
    // [6] Cx hi/lo
    combine_cvt_kernel<<<dim3(512), dim3(256), 0, stream>>>(Ep, Cxh, Cxl);
    // [7] out-GEMM partials (K=2048 split 4)
    mfma_out_kernel<<<dim3(16, 8, 4), dim3(256), 0, stream>>>(
        Qh, Ql, Cxh, Cxl, Woh, Wol, Fp);
    // [8] out = tanh(sum + bout)
    tanh_combine_kernel<<<dim3(512), dim3(256), 0, stream>>>(Fp, bout, out);
}